// Round 4
// baseline (54.572 us; speedup 1.0000x reference)
//
#include <hip/hip_runtime.h>

#define FH 128
#define FW 128
#define OUT_DIM 10
#define CPLANE 490          // 10*7*7 input channels; plane c_in serves bin (ph,pw)
#define NBATCH 4
#define SSCALE 0.0625f

// ---- kernel A: bucket roi indices by batch into d_ws -----------------------
// ws layout: ws[0..3] = counts, ws[4 + b*R + slot] = roi index
__global__ __launch_bounds__(1024) void bucket_rois(const float* __restrict__ rois,
                                                    int R, int* __restrict__ ws) {
    __shared__ int cnt[NBATCH];
    if (threadIdx.x < NBATCH) cnt[threadIdx.x] = 0;
    __syncthreads();
    for (int i = threadIdx.x; i < R; i += blockDim.x) {
        int b = (int)rois[(size_t)i * 5];
        int slot = atomicAdd(&cnt[b], 1);
        ws[NBATCH + b * R + slot] = i;
    }
    __syncthreads();
    if (threadIdx.x < NBATCH) ws[threadIdx.x] = cnt[threadIdx.x];
}

// ---- kernel B: one block per (c_in, b) plane --------------------------------
// Stage the 64KB plane in LDS (coalesced, read exactly once), then gather all
// rois of batch b: 4 lanes per roi (one per bilinear sample), shfl-reduce.
__global__ __launch_bounds__(256) void psroi_gather(const float* __restrict__ feat,
                                                    const float* __restrict__ rois,
                                                    const int* __restrict__ ws,
                                                    float* __restrict__ out, int R) {
    const int c_in = blockIdx.x;
    const int b    = blockIdx.y;

    __shared__ float plane[FH * FW];   // 64 KB

    // ---- stream plane (b, c_in) into LDS, float4-coalesced ----
    const float* __restrict__ src = feat + ((size_t)b * CPLANE + c_in) * (FH * FW);
#pragma unroll
    for (int it = 0; it < 16; ++it) {
        const int idx = (it * 256 + threadIdx.x) * 4;
        const float4 v = *(const float4*)(src + idx);
        *(float4*)(plane + idx) = v;
    }
    __syncthreads();

    // ---- gather phase ----
    const int  nb   = ws[b];
    const int* list = ws + NBATCH + b * R;
    const int  pw   = c_in % 7;
    const int  ph   = (c_in / 7) % 7;

    const int   sub = threadIdx.x & 3;           // sample id (iy,ix)
    const float sy  = 0.25f + 0.5f * (float)(sub >> 1);
    const float sx  = 0.25f + 0.5f * (float)(sub & 1);

    for (int base = 0; base < nb; base += 64) {
        const int  k      = base + (threadIdx.x >> 2);
        const bool active = (k < nb);
        const int  ri     = active ? list[k] : 0;

        const float* roi = rois + (size_t)ri * 5;
        const float x1 = roi[1] * SSCALE;
        const float y1 = roi[2] * SSCALE;
        const float bw = fmaxf(roi[3] * SSCALE - x1, 0.1f) * (1.0f / 7.0f);
        const float bh = fmaxf(roi[4] * SSCALE - y1, 0.1f) * (1.0f / 7.0f);

        float y = y1 + ((float)ph + sy) * bh;
        y = fminf(fmaxf(y, 0.0f), 127.0f);
        float y0f = floorf(y);
        int   y0  = (int)y0f;
        float ly  = y - y0f;
        if (y0 > 126) { y0 = 126; ly = 1.0f; }   // y==127 -> full weight on row 127

        float x = x1 + ((float)pw + sx) * bw;
        x = fminf(fmaxf(x, 0.0f), 127.0f);
        float x0f = floorf(x);
        int   x0  = (int)x0f;
        float lx  = x - x0f;
        if (x0 > 126) { x0 = 126; lx = 1.0f; }

        const float* p = plane + y0 * FW + x0;
        const float v00 = p[0];
        const float v01 = p[1];
        const float v10 = p[FW];
        const float v11 = p[FW + 1];

        const float top = v00 + (v01 - v00) * lx;
        const float bot = v10 + (v11 - v10) * lx;
        float val = top + (bot - top) * ly;

        // reduce the 4 samples of this roi's bin, average
        val += __shfl_xor(val, 1);
        val += __shfl_xor(val, 2);
        if (active && sub == 0) out[(size_t)ri * CPLANE + c_in] = val * 0.25f;
    }
}

extern "C" void kernel_launch(void* const* d_in, const int* in_sizes, int n_in,
                              void* d_out, int out_size, void* d_ws, size_t ws_size,
                              hipStream_t stream) {
    const float* feat = (const float*)d_in[0];
    const float* rois = (const float*)d_in[1];
    float* out = (float*)d_out;
    int* ws = (int*)d_ws;

    const int R = in_sizes[1] / 5;   // 2048

    bucket_rois<<<1, 1024, 0, stream>>>(rois, R, ws);

    dim3 grid(CPLANE, NBATCH);       // (490, 4)
    psroi_gather<<<grid, 256, 0, stream>>>(feat, rois, ws, out, R);
}